// Round 1
// baseline (307.502 us; speedup 1.0000x reference)
//
#include <hip/hip_runtime.h>

#define NN 100000
#define EE 1600000
#define FDIM 224
#define OUTC 112

typedef __attribute__((ext_vector_type(8))) short bf16x8;
typedef __attribute__((ext_vector_type(4))) float f32x4;
typedef __attribute__((ext_vector_type(4))) unsigned short u16x4;

__device__ __forceinline__ unsigned short f2bf(float f) {
  unsigned u = __builtin_bit_cast(unsigned, f);
  u = (u + 0x7FFFu + ((u >> 16) & 1u)) >> 16;   // RNE
  return (unsigned short)u;
}
__device__ __forceinline__ float bf2f(unsigned short h) {
  return __builtin_bit_cast(float, (unsigned)h << 16);
}

// ---- prep kernels ------------------------------------------------------
__global__ void k_zero(unsigned int* p, int n) {
  int i = blockIdx.x * 256 + threadIdx.x;
  if (i < n) p[i] = 0u;
}

__global__ void k_scatter(const int* __restrict__ ei, unsigned char* __restrict__ act) {
  int e = blockIdx.x * 256 + threadIdx.x;
  if (e < EE) act[ei[e]] = 1;   // ei[0..E) is edge_index[0]
}

// W1T: [512][128] bf16  (cols of [invW1 | wembW1], each row k-contiguous)
// W2T: [576][256] bf16  (rows 0..63 = invW2 cols, 64..575 = wembW2 cols)
__global__ void k_wprep(const float* __restrict__ invW1, const float* __restrict__ invW2,
                        const float* __restrict__ wembW1, const float* __restrict__ wembW2,
                        unsigned short* __restrict__ W1T, unsigned short* __restrict__ W2T) {
  int i = blockIdx.x * 256 + threadIdx.x;
  if (i < 512 * 128) {
    int n = i >> 7, k = i & 127;
    float v = (n < 256) ? invW1[k * 256 + n] : wembW1[k * 256 + (n - 256)];
    W1T[i] = f2bf(v);
  } else if (i < 512 * 128 + 576 * 256) {
    int t = i - 512 * 128;
    int n = t >> 8, k = t & 255;
    float v = (n < 64) ? invW2[k * 64 + n] : wembW2[k * 512 + (n - 64)];
    W2T[t] = f2bf(v);
  }
}

// ---- fused main kernel -------------------------------------------------
// 64 nodes / block, 256 threads (4 waves). LDS: 64 rows x 512 bf16 (64KB),
// XOR-swizzled (byte ^= (row&7)<<4) to kill the stride-1024B bank conflict.
__global__ __launch_bounds__(256, 2) void k_main(
    const float* __restrict__ feats,
    const unsigned short* __restrict__ W1T,
    const unsigned short* __restrict__ W2T,
    const unsigned char* __restrict__ act,
    float* __restrict__ out) {
  __shared__ char smem[65536];
  const int tid = threadIdx.x;
  const int lane = tid & 63;
  const int wv = tid >> 6;       // wave 0..3
  const int o = lane & 15;       // col within 16x16 tile
  const int g = lane >> 4;       // lane group (k-group / row-group)
  const int base = blockIdx.x * 64;

  const float rs128 = 0.08838834764831845f;   // 1/sqrt(128)
  const float inv16 = 0.0625f;                // 1/sqrt(256)
  const float rs32  = 0.17677669529663687f;   // 1/sqrt(32)

  // ================= Phase A: H = silu(S @ W1cat / sqrt(128)) ==========
  f32x4 acc[4][8];
#pragma unroll
  for (int mt = 0; mt < 4; ++mt)
#pragma unroll
    for (int nt = 0; nt < 8; ++nt)
      acc[mt][nt] = (f32x4){0.f, 0.f, 0.f, 0.f};

  const float* arow[4];
#pragma unroll
  for (int mt = 0; mt < 4; ++mt) {
    int r = base + mt * 16 + o;
    if (r > NN - 1) r = NN - 1;   // clamp tail rows (stores are guarded)
    arow[mt] = feats + r * FDIM;
  }

#pragma unroll
  for (int ks = 0; ks < 4; ++ks) {
    bf16x8 af[4];
#pragma unroll
    for (int mt = 0; mt < 4; ++mt) {
      const float* p = arow[mt] + ks * 32 + g * 8;
      f32x4 x0 = *(const f32x4*)p;
      f32x4 x1 = *(const f32x4*)(p + 4);
      bf16x8 a;
      a[0] = (short)f2bf(x0[0]); a[1] = (short)f2bf(x0[1]);
      a[2] = (short)f2bf(x0[2]); a[3] = (short)f2bf(x0[3]);
      a[4] = (short)f2bf(x1[0]); a[5] = (short)f2bf(x1[1]);
      a[6] = (short)f2bf(x1[2]); a[7] = (short)f2bf(x1[3]);
      af[mt] = a;
    }
#pragma unroll
    for (int nt = 0; nt < 8; ++nt) {
      int n = wv * 128 + nt * 16 + o;
      bf16x8 b = *(const bf16x8*)(W1T + n * 128 + ks * 32 + g * 8);
#pragma unroll
      for (int mt = 0; mt < 4; ++mt)
        acc[mt][nt] = __builtin_amdgcn_mfma_f32_16x16x32_bf16(af[mt], b, acc[mt][nt], 0, 0, 0);
    }
  }

  // silu + bf16 -> LDS (swizzled)
#pragma unroll
  for (int mt = 0; mt < 4; ++mt)
#pragma unroll
    for (int nt = 0; nt < 8; ++nt)
#pragma unroll
      for (int r4 = 0; r4 < 4; ++r4) {
        int row = mt * 16 + g * 4 + r4;
        int col = wv * 128 + nt * 16 + o;
        float v = acc[mt][nt][r4] * rs128;
        float h = v / (1.f + __expf(-v));
        int byte = (row * 1024 + col * 2) ^ ((row & 7) << 4);
        *(unsigned short*)(smem + byte) = f2bf(h);
      }
  __syncthreads();

  // ================= Phase B1: Wm = H2 @ wembW2 (K = H cols 256..512) ===
#pragma unroll
  for (int mt = 0; mt < 4; ++mt)
#pragma unroll
    for (int nt = 0; nt < 8; ++nt)
      acc[mt][nt] = (f32x4){0.f, 0.f, 0.f, 0.f};

#pragma unroll
  for (int ks = 0; ks < 8; ++ks) {
    bf16x8 af[4];
#pragma unroll
    for (int mt = 0; mt < 4; ++mt) {
      int row = mt * 16 + o;
      int byte = (row * 1024 + (256 + ks * 32 + g * 8) * 2) ^ ((row & 7) << 4);
      af[mt] = *(const bf16x8*)(smem + byte);
    }
#pragma unroll
    for (int nt = 0; nt < 8; ++nt) {
      int wc = wv * 128 + nt * 16 + o;                       // wemb col 0..511
      bf16x8 b = *(const bf16x8*)(W2T + 64 * 256 + wc * 256 + ks * 32 + g * 8);
#pragma unroll
      for (int mt = 0; mt < 4; ++mt)
        acc[mt][nt] = __builtin_amdgcn_mfma_f32_16x16x32_bf16(af[mt], b, acc[mt][nt], 0, 0, 0);
    }
  }

  // ================= Phase B2: inv_out = H1 @ invW2 (K = H cols 0..256) =
  f32x4 acc2[4];
#pragma unroll
  for (int mt = 0; mt < 4; ++mt) acc2[mt] = (f32x4){0.f, 0.f, 0.f, 0.f};

#pragma unroll
  for (int ks = 0; ks < 8; ++ks) {
    bf16x8 af[4];
#pragma unroll
    for (int mt = 0; mt < 4; ++mt) {
      int row = mt * 16 + o;
      int byte = (row * 1024 + (ks * 32 + g * 8) * 2) ^ ((row & 7) << 4);
      af[mt] = *(const bf16x8*)(smem + byte);
    }
    int c = wv * 16 + o;                                    // inv col 0..63
    bf16x8 b = *(const bf16x8*)(W2T + c * 256 + ks * 32 + g * 8);
#pragma unroll
    for (int mt = 0; mt < 4; ++mt)
      acc2[mt] = __builtin_amdgcn_mfma_f32_16x16x32_bf16(af[mt], b, acc2[mt], 0, 0, 0);
  }

  // inv output (cols 0..63), masked
#pragma unroll
  for (int mt = 0; mt < 4; ++mt)
#pragma unroll
    for (int r4 = 0; r4 < 4; ++r4) {
      int node = base + mt * 16 + g * 4 + r4;
      if (node < NN) {
        float s = act[node] ? inv16 : 0.f;
        out[node * OUTC + wv * 16 + o] = acc2[mt][r4] * s;
      }
    }
  __syncthreads();   // all H reads done -> LDS reusable

  // wemb accs -> LDS as bf16 (scaled by 1/16), same swizzle
#pragma unroll
  for (int mt = 0; mt < 4; ++mt)
#pragma unroll
    for (int nt = 0; nt < 8; ++nt)
#pragma unroll
      for (int r4 = 0; r4 < 4; ++r4) {
        int row = mt * 16 + g * 4 + r4;
        int col = wv * 128 + nt * 16 + o;
        int byte = (row * 1024 + col * 2) ^ ((row & 7) << 4);
        *(unsigned short*)(smem + byte) = f2bf(acc[mt][nt][r4] * inv16);
      }
  __syncthreads();

  // ================= Phase C: einsum eq[n,o,m] = sum_i x[n,i,m]*w[n,i,o] =
  int nloc = tid >> 2;
  int q = tid & 3;           // handles o in [q*4, q*4+4)
  int node = base + nloc;
  if (node >= NN) return;

  const float* xp = feats + node * FDIM + 128;
  float x[96];
#pragma unroll
  for (int j = 0; j < 24; ++j) {
    f32x4 v = *(const f32x4*)(xp + j * 4);
    x[j * 4 + 0] = v[0]; x[j * 4 + 1] = v[1];
    x[j * 4 + 2] = v[2]; x[j * 4 + 3] = v[3];
  }

  float eq[12];
#pragma unroll
  for (int j = 0; j < 12; ++j) eq[j] = 0.f;

#pragma unroll
  for (int i = 0; i < 32; ++i) {
    int byte = (nloc * 1024 + (i * 16 + q * 4) * 2) ^ ((nloc & 7) << 4);
    u16x4 w4 = *(const u16x4*)(smem + byte);
#pragma unroll
    for (int t = 0; t < 4; ++t) {
      float wf = bf2f(w4[t]);
      eq[t * 3 + 0] += x[i * 3 + 0] * wf;
      eq[t * 3 + 1] += x[i * 3 + 1] * wf;
      eq[t * 3 + 2] += x[i * 3 + 2] * wf;
    }
  }

  float s = act[node] ? rs32 : 0.f;
  float* op = out + node * OUTC + 64 + q * 12;
  f32x4 v0 = {eq[0] * s, eq[1] * s, eq[2] * s, eq[3] * s};
  f32x4 v1 = {eq[4] * s, eq[5] * s, eq[6] * s, eq[7] * s};
  f32x4 v2 = {eq[8] * s, eq[9] * s, eq[10] * s, eq[11] * s};
  *(f32x4*)(op + 0) = v0;
  *(f32x4*)(op + 4) = v1;
  *(f32x4*)(op + 8) = v2;
}

// ---- launch ------------------------------------------------------------
extern "C" void kernel_launch(void* const* d_in, const int* in_sizes, int n_in,
                              void* d_out, int out_size, void* d_ws, size_t ws_size,
                              hipStream_t stream) {
  const float* feats = (const float*)d_in[0];
  const int* ei = (const int*)d_in[1];
  const float* invW1 = (const float*)d_in[2];
  const float* invW2 = (const float*)d_in[3];
  const float* wembW1 = (const float*)d_in[4];
  const float* wembW2 = (const float*)d_in[5];
  float* out = (float*)d_out;

  char* ws = (char*)d_ws;
  unsigned short* W1T = (unsigned short*)ws;                    // 131072 B
  unsigned short* W2T = (unsigned short*)(ws + 131072);         // 294912 B
  unsigned char* act = (unsigned char*)(ws + 131072 + 294912);  // 100000 B

  k_zero<<<98, 256, 0, stream>>>((unsigned int*)act, 25000);
  k_scatter<<<6250, 256, 0, stream>>>(ei, act);
  k_wprep<<<832, 256, 0, stream>>>(invW1, invW2, wembW1, wembW2, W1T, W2T);
  k_main<<<1563, 256, 0, stream>>>(feats, W1T, W2T, act, out);
}

// Round 2
// 294.858 us; speedup vs baseline: 1.0429x; 1.0429x over previous
//
#include <hip/hip_runtime.h>

#define NN 100000
#define EE 1600000
#define FDIM 224
#define OUTC 112

typedef __attribute__((ext_vector_type(8))) short bf16x8;
typedef __attribute__((ext_vector_type(4))) float f32x4;
typedef __attribute__((ext_vector_type(2))) float f32x2;
typedef __attribute__((ext_vector_type(2))) unsigned short u16x2;

__device__ __forceinline__ unsigned short f2bf(float f) {
  unsigned u = __builtin_bit_cast(unsigned, f);
  u = (u + 0x7FFFu + ((u >> 16) & 1u)) >> 16;   // RNE
  return (unsigned short)u;
}
__device__ __forceinline__ float bf2f(unsigned short h) {
  return __builtin_bit_cast(float, (unsigned)h << 16);
}

// ---- prep kernels ------------------------------------------------------
__global__ void k_zero(unsigned int* p, int n) {
  int i = blockIdx.x * 256 + threadIdx.x;
  if (i < n) p[i] = 0u;
}

__global__ void k_scatter(const int* __restrict__ ei, unsigned char* __restrict__ act) {
  int e = blockIdx.x * 256 + threadIdx.x;
  if (e < EE) act[ei[e]] = 1;   // ei[0..E) is edge_index[0]
}

// W1T: [512][128] bf16  (cols of [invW1 | wembW1], each row k-contiguous)
// W2T: [576][256] bf16  (rows 0..63 = invW2 cols, 64..575 = wembW2 cols)
__global__ void k_wprep(const float* __restrict__ invW1, const float* __restrict__ invW2,
                        const float* __restrict__ wembW1, const float* __restrict__ wembW2,
                        unsigned short* __restrict__ W1T, unsigned short* __restrict__ W2T) {
  int i = blockIdx.x * 256 + threadIdx.x;
  if (i < 512 * 128) {
    int n = i >> 7, k = i & 127;
    float v = (n < 256) ? invW1[k * 256 + n] : wembW1[k * 256 + (n - 256)];
    W1T[i] = f2bf(v);
  } else if (i < 512 * 128 + 576 * 256) {
    int t = i - 512 * 128;
    int n = t >> 8, k = t & 255;
    float v = (n < 64) ? invW2[k * 64 + n] : wembW2[k * 512 + (n - 64)];
    W2T[t] = f2bf(v);
  }
}

// ---- fused main kernel -------------------------------------------------
// 32 nodes / block, 256 threads (4 waves). LDS: 32 rows x 512 bf16 (32KB),
// XOR-swizzled (byte ^= (row&7)<<4). 100000 = 3125*32 -> no tail guards.
__global__ __launch_bounds__(256, 4) void k_main(
    const float* __restrict__ feats,
    const unsigned short* __restrict__ W1T,
    const unsigned short* __restrict__ W2T,
    const unsigned char* __restrict__ act,
    float* __restrict__ out) {
  __shared__ char smem[32768];
  const int tid = threadIdx.x;
  const int lane = tid & 63;
  const int wv = tid >> 6;       // wave 0..3
  const int o = lane & 15;       // col within 16x16 tile
  const int g = lane >> 4;       // lane group (k-group / row-group)
  const int base = blockIdx.x * 32;

  const float rs128 = 0.08838834764831845f;   // 1/sqrt(128)
  const float inv16 = 0.0625f;                // 1/sqrt(256)
  const float rs32  = 0.17677669529663687f;   // 1/sqrt(32)

  // ================= Phase A: H = silu(S @ W1cat / sqrt(128)) ==========
  f32x4 acc[2][8];
#pragma unroll
  for (int mt = 0; mt < 2; ++mt)
#pragma unroll
    for (int nt = 0; nt < 8; ++nt)
      acc[mt][nt] = (f32x4){0.f, 0.f, 0.f, 0.f};

  const float* arow[2] = {feats + (size_t)(base + o) * FDIM,
                          feats + (size_t)(base + 16 + o) * FDIM};

#pragma unroll
  for (int ks = 0; ks < 4; ++ks) {
    bf16x8 af[2];
#pragma unroll
    for (int mt = 0; mt < 2; ++mt) {
      const float* p = arow[mt] + ks * 32 + g * 8;
      f32x4 x0 = *(const f32x4*)p;
      f32x4 x1 = *(const f32x4*)(p + 4);
      bf16x8 a;
      a[0] = (short)f2bf(x0[0]); a[1] = (short)f2bf(x0[1]);
      a[2] = (short)f2bf(x0[2]); a[3] = (short)f2bf(x0[3]);
      a[4] = (short)f2bf(x1[0]); a[5] = (short)f2bf(x1[1]);
      a[6] = (short)f2bf(x1[2]); a[7] = (short)f2bf(x1[3]);
      af[mt] = a;
    }
#pragma unroll
    for (int nt = 0; nt < 8; ++nt) {
      int n = wv * 128 + nt * 16 + o;
      bf16x8 b = *(const bf16x8*)(W1T + n * 128 + ks * 32 + g * 8);
#pragma unroll
      for (int mt = 0; mt < 2; ++mt)
        acc[mt][nt] = __builtin_amdgcn_mfma_f32_16x16x32_bf16(af[mt], b, acc[mt][nt], 0, 0, 0);
    }
  }

  // silu + bf16 -> LDS (swizzled)
#pragma unroll
  for (int mt = 0; mt < 2; ++mt)
#pragma unroll
    for (int nt = 0; nt < 8; ++nt)
#pragma unroll
      for (int r4 = 0; r4 < 4; ++r4) {
        int row = mt * 16 + g * 4 + r4;
        int col = wv * 128 + nt * 16 + o;
        float v = acc[mt][nt][r4] * rs128;
        float h = v / (1.f + __expf(-v));
        int byte = (row * 1024 + col * 2) ^ ((row & 7) << 4);
        *(unsigned short*)(smem + byte) = f2bf(h);
      }
  __syncthreads();

  // ================= Phase B1: Wm = H2 @ wembW2 (K = H cols 256..512) ===
#pragma unroll
  for (int mt = 0; mt < 2; ++mt)
#pragma unroll
    for (int nt = 0; nt < 8; ++nt)
      acc[mt][nt] = (f32x4){0.f, 0.f, 0.f, 0.f};

#pragma unroll
  for (int ks = 0; ks < 8; ++ks) {
    bf16x8 af[2];
#pragma unroll
    for (int mt = 0; mt < 2; ++mt) {
      int row = mt * 16 + o;
      int byte = (row * 1024 + (256 + ks * 32 + g * 8) * 2) ^ ((row & 7) << 4);
      af[mt] = *(const bf16x8*)(smem + byte);
    }
#pragma unroll
    for (int nt = 0; nt < 8; ++nt) {
      int wc = wv * 128 + nt * 16 + o;                       // wemb col 0..511
      bf16x8 b = *(const bf16x8*)(W2T + 64 * 256 + wc * 256 + ks * 32 + g * 8);
#pragma unroll
      for (int mt = 0; mt < 2; ++mt)
        acc[mt][nt] = __builtin_amdgcn_mfma_f32_16x16x32_bf16(af[mt], b, acc[mt][nt], 0, 0, 0);
    }
  }

  // ================= Phase B2: inv_out = H1 @ invW2 (K = H cols 0..256) =
  f32x4 acc2[2];
#pragma unroll
  for (int mt = 0; mt < 2; ++mt) acc2[mt] = (f32x4){0.f, 0.f, 0.f, 0.f};

#pragma unroll
  for (int ks = 0; ks < 8; ++ks) {
    bf16x8 af[2];
#pragma unroll
    for (int mt = 0; mt < 2; ++mt) {
      int row = mt * 16 + o;
      int byte = (row * 1024 + (ks * 32 + g * 8) * 2) ^ ((row & 7) << 4);
      af[mt] = *(const bf16x8*)(smem + byte);
    }
    int c = wv * 16 + o;                                    // inv col 0..63
    bf16x8 b = *(const bf16x8*)(W2T + c * 256 + ks * 32 + g * 8);
#pragma unroll
    for (int mt = 0; mt < 2; ++mt)
      acc2[mt] = __builtin_amdgcn_mfma_f32_16x16x32_bf16(af[mt], b, acc2[mt], 0, 0, 0);
  }

  // inv output (cols 0..63), masked
#pragma unroll
  for (int mt = 0; mt < 2; ++mt)
#pragma unroll
    for (int r4 = 0; r4 < 4; ++r4) {
      int node = base + mt * 16 + g * 4 + r4;
      float s = act[node] ? inv16 : 0.f;
      out[(size_t)node * OUTC + wv * 16 + o] = acc2[mt][r4] * s;
    }
  __syncthreads();   // all H reads done -> LDS reusable

  // wemb accs -> LDS as bf16 (scaled by 1/16), same swizzle
#pragma unroll
  for (int mt = 0; mt < 2; ++mt)
#pragma unroll
    for (int nt = 0; nt < 8; ++nt)
#pragma unroll
      for (int r4 = 0; r4 < 4; ++r4) {
        int row = mt * 16 + g * 4 + r4;
        int col = wv * 128 + nt * 16 + o;
        int byte = (row * 1024 + col * 2) ^ ((row & 7) << 4);
        *(unsigned short*)(smem + byte) = f2bf(acc[mt][nt][r4] * inv16);
      }
  __syncthreads();

  // ================= Phase C: einsum eq[n,o,m] = sum_i x[n,i,m]*w[n,i,o] =
  // 8 threads per node; thread q handles o in {2q, 2q+1}. x processed in
  // 12-float chunks so nothing spills.
  const int nloc = tid >> 3;
  const int q = tid & 7;
  const int node = base + nloc;

  const float* xp = feats + (size_t)node * FDIM + 128;

  float eq[6];
#pragma unroll
  for (int j = 0; j < 6; ++j) eq[j] = 0.f;

#pragma unroll 2
  for (int i4 = 0; i4 < 8; ++i4) {
    const float* p = xp + i4 * 12;
    f32x4 x0 = *(const f32x4*)(p);
    f32x4 x1 = *(const f32x4*)(p + 4);
    f32x4 x2 = *(const f32x4*)(p + 8);
    float xx[12] = {x0[0], x0[1], x0[2], x0[3], x1[0], x1[1],
                    x1[2], x1[3], x2[0], x2[1], x2[2], x2[3]};
#pragma unroll
    for (int di = 0; di < 4; ++di) {
      int i = i4 * 4 + di;
      int byte = (nloc * 1024 + i * 32 + q * 4) ^ ((nloc & 7) << 4);
      u16x2 w2 = *(const u16x2*)(smem + byte);
      float wf0 = bf2f(w2[0]);
      float wf1 = bf2f(w2[1]);
#pragma unroll
      for (int m = 0; m < 3; ++m) {
        float xv = xx[di * 3 + m];
        eq[0 * 3 + m] += xv * wf0;
        eq[1 * 3 + m] += xv * wf1;
      }
    }
  }

  float s = act[node] ? rs32 : 0.f;
  float* op = out + (size_t)node * OUTC + 64 + q * 6;
  f32x2 v0 = {eq[0] * s, eq[1] * s};
  f32x2 v1 = {eq[2] * s, eq[3] * s};
  f32x2 v2 = {eq[4] * s, eq[5] * s};
  *(f32x2*)(op + 0) = v0;
  *(f32x2*)(op + 2) = v1;
  *(f32x2*)(op + 4) = v2;
}

// ---- launch ------------------------------------------------------------
extern "C" void kernel_launch(void* const* d_in, const int* in_sizes, int n_in,
                              void* d_out, int out_size, void* d_ws, size_t ws_size,
                              hipStream_t stream) {
  const float* feats = (const float*)d_in[0];
  const int* ei = (const int*)d_in[1];
  const float* invW1 = (const float*)d_in[2];
  const float* invW2 = (const float*)d_in[3];
  const float* wembW1 = (const float*)d_in[4];
  const float* wembW2 = (const float*)d_in[5];
  float* out = (float*)d_out;

  char* ws = (char*)d_ws;
  unsigned short* W1T = (unsigned short*)ws;                    // 131072 B
  unsigned short* W2T = (unsigned short*)(ws + 131072);         // 294912 B
  unsigned char* act = (unsigned char*)(ws + 131072 + 294912);  // 100000 B

  k_zero<<<98, 256, 0, stream>>>((unsigned int*)act, 25000);
  k_scatter<<<6250, 256, 0, stream>>>(ei, act);
  k_wprep<<<832, 256, 0, stream>>>(invW1, invW2, wembW1, wembW2, W1T, W2T);
  k_main<<<3125, 256, 0, stream>>>(feats, W1T, W2T, act, out);
}

// Round 3
// 250.997 us; speedup vs baseline: 1.2251x; 1.1747x over previous
//
#include <hip/hip_runtime.h>

#define NN 100000
#define EE 1600000
#define FDIM 224
#define OUTC 112

typedef __attribute__((ext_vector_type(8))) short bf16x8;
typedef __attribute__((ext_vector_type(4))) float f32x4;

__device__ __forceinline__ unsigned short f2bf(float f) {
  unsigned u = __builtin_bit_cast(unsigned, f);
  u = (u + 0x7FFFu + ((u >> 16) & 1u)) >> 16;   // RNE
  return (unsigned short)u;
}
__device__ __forceinline__ float bf2f(unsigned short h) {
  return __builtin_bit_cast(float, (unsigned)h << 16);
}

// ---- prep kernels ------------------------------------------------------
__global__ void k_zero(unsigned int* p, int n) {
  int i = blockIdx.x * 256 + threadIdx.x;
  if (i < n) p[i] = 0u;
}

__global__ void k_scatter(const int* __restrict__ ei, unsigned char* __restrict__ act) {
  int e = blockIdx.x * 256 + threadIdx.x;
  if (e < EE) act[ei[e]] = 1;   // ei[0..E) is edge_index[0]
}

// W1T: [512][128] bf16  (cols of [invW1 | wembW1], each row k-contiguous)
// W2T: [576][256] bf16  (rows 0..63 = invW2 cols, 64..575 = wembW2 cols)
__global__ void k_wprep(const float* __restrict__ invW1, const float* __restrict__ invW2,
                        const float* __restrict__ wembW1, const float* __restrict__ wembW2,
                        unsigned short* __restrict__ W1T, unsigned short* __restrict__ W2T) {
  int i = blockIdx.x * 256 + threadIdx.x;
  if (i < 512 * 128) {
    int n = i >> 7, k = i & 127;
    float v = (n < 256) ? invW1[k * 256 + n] : wembW1[k * 256 + (n - 256)];
    W1T[i] = f2bf(v);
  } else if (i < 512 * 128 + 576 * 256) {
    int t = i - 512 * 128;
    int n = t >> 8, k = t & 255;
    float v = (n < 64) ? invW2[k * 64 + n] : wembW2[k * 512 + (n - 64)];
    W2T[t] = f2bf(v);
  }
}

// ---- fused main kernel -------------------------------------------------
// 32 nodes / block, 512 threads (8 waves). LDS: 32 rows x 512 bf16 (32KB),
// XOR-swizzled (byte ^= (row&15)<<4): 16 rows -> 16 distinct 16B slots, so
// stride-1024B ds_read_b128 column reads are conflict-free.
__global__ __launch_bounds__(512, 4) void k_main(
    const float* __restrict__ feats,
    const unsigned short* __restrict__ W1T,
    const unsigned short* __restrict__ W2T,
    const unsigned char* __restrict__ act,
    float* __restrict__ out) {
  __shared__ char smem[32768];
  const int tid = threadIdx.x;
  const int lane = tid & 63;
  const int wv = tid >> 6;       // wave 0..7
  const int o = lane & 15;       // col within 16x16 tile
  const int g = lane >> 4;       // lane group (k-group / row-group)
  const int base = blockIdx.x * 32;

  const float rs128 = 0.08838834764831845f;   // 1/sqrt(128)
  const float inv16 = 0.0625f;                // 1/sqrt(256)
  const float rs32  = 0.17677669529663687f;   // 1/sqrt(32)

  // ================= Phase A: H = silu(S @ W1cat / sqrt(128)) ==========
  // Each wave: 2 row-tiles x 4 col-tiles (cols wv*64 .. wv*64+63).
  f32x4 acc[2][4];
#pragma unroll
  for (int mt = 0; mt < 2; ++mt)
#pragma unroll
    for (int nt = 0; nt < 4; ++nt)
      acc[mt][nt] = (f32x4){0.f, 0.f, 0.f, 0.f};

  const float* arow0 = feats + (size_t)(base + o) * FDIM;
  const float* arow1 = arow0 + 16 * FDIM;

#pragma unroll 1
  for (int ks = 0; ks < 4; ++ks) {
    bf16x8 af[2];
#pragma unroll
    for (int mt = 0; mt < 2; ++mt) {
      const float* p = (mt ? arow1 : arow0) + ks * 32 + g * 8;
      f32x4 x0 = *(const f32x4*)p;
      f32x4 x1 = *(const f32x4*)(p + 4);
      bf16x8 a;
      a[0] = (short)f2bf(x0[0]); a[1] = (short)f2bf(x0[1]);
      a[2] = (short)f2bf(x0[2]); a[3] = (short)f2bf(x0[3]);
      a[4] = (short)f2bf(x1[0]); a[5] = (short)f2bf(x1[1]);
      a[6] = (short)f2bf(x1[2]); a[7] = (short)f2bf(x1[3]);
      af[mt] = a;
    }
#pragma unroll
    for (int nt = 0; nt < 4; ++nt) {
      int n = wv * 64 + nt * 16 + o;
      bf16x8 b = *(const bf16x8*)(W1T + n * 128 + ks * 32 + g * 8);
#pragma unroll
      for (int mt = 0; mt < 2; ++mt)
        acc[mt][nt] = __builtin_amdgcn_mfma_f32_16x16x32_bf16(af[mt], b, acc[mt][nt], 0, 0, 0);
    }
  }

  // silu + bf16 -> LDS (swizzled)
#pragma unroll
  for (int mt = 0; mt < 2; ++mt)
#pragma unroll
    for (int nt = 0; nt < 4; ++nt)
#pragma unroll
      for (int r4 = 0; r4 < 4; ++r4) {
        int row = mt * 16 + g * 4 + r4;
        int col = wv * 64 + nt * 16 + o;
        float v = acc[mt][nt][r4] * rs128;
        float h = v / (1.f + __expf(-v));
        int byte = (row * 1024 + col * 2) ^ ((row & 15) << 4);
        *(unsigned short*)(smem + byte) = f2bf(h);
      }
  __syncthreads();

  // ================= Phase B2 first: inv_out = H1 @ invW2 (K=cols 0..255)
  // One 16x16 tile per wave: rows (wv&1)*16.., cols (wv>>1)*16..
  {
    const int mtw = wv & 1;
    const int cw = (wv >> 2) * 16 + o;        // need 4 col-tiles: wv>>1 in 0..3
    // NOTE: 8 waves = 2 row-tiles x 4 col-tiles -> mtw = wv&1, ct = wv>>1
    const int ct = wv >> 1;                   // 0..3
    f32x4 acc2 = (f32x4){0.f, 0.f, 0.f, 0.f};
    (void)cw;
#pragma unroll 1
    for (int ks = 0; ks < 8; ++ks) {
      int row = mtw * 16 + o;
      int byte = (row * 1024 + ks * 64 + g * 16) ^ ((row & 15) << 4);
      bf16x8 af = *(const bf16x8*)(smem + byte);
      bf16x8 b = *(const bf16x8*)(W2T + (ct * 16 + o) * 256 + ks * 32 + g * 8);
      acc2 = __builtin_amdgcn_mfma_f32_16x16x32_bf16(af, b, acc2, 0, 0, 0);
    }
#pragma unroll
    for (int r4 = 0; r4 < 4; ++r4) {
      int node = base + mtw * 16 + g * 4 + r4;
      float s = act[node] ? inv16 : 0.f;
      __builtin_nontemporal_store(acc2[r4] * s, out + (size_t)node * OUTC + ct * 16 + o);
    }
  }

  // ================= Phase B1: Wm = H2 @ wembW2 (K = H cols 256..511) ===
#pragma unroll
  for (int mt = 0; mt < 2; ++mt)
#pragma unroll
    for (int nt = 0; nt < 4; ++nt)
      acc[mt][nt] = (f32x4){0.f, 0.f, 0.f, 0.f};

#pragma unroll 1
  for (int ks = 0; ks < 8; ++ks) {
    bf16x8 af[2];
#pragma unroll
    for (int mt = 0; mt < 2; ++mt) {
      int row = mt * 16 + o;
      int byte = (row * 1024 + 512 + ks * 64 + g * 16) ^ ((row & 15) << 4);
      af[mt] = *(const bf16x8*)(smem + byte);
    }
#pragma unroll
    for (int nt = 0; nt < 4; ++nt) {
      int wc = wv * 64 + nt * 16 + o;                       // wemb col 0..511
      bf16x8 b = *(const bf16x8*)(W2T + 64 * 256 + wc * 256 + ks * 32 + g * 8);
#pragma unroll
      for (int mt = 0; mt < 2; ++mt)
        acc[mt][nt] = __builtin_amdgcn_mfma_f32_16x16x32_bf16(af[mt], b, acc[mt][nt], 0, 0, 0);
    }
  }
  __syncthreads();   // all H reads done -> LDS reusable

  // wemb accs -> LDS as bf16 (scaled by 1/16), same swizzle
#pragma unroll
  for (int mt = 0; mt < 2; ++mt)
#pragma unroll
    for (int nt = 0; nt < 4; ++nt)
#pragma unroll
      for (int r4 = 0; r4 < 4; ++r4) {
        int row = mt * 16 + g * 4 + r4;
        int col = wv * 64 + nt * 16 + o;
        int byte = (row * 1024 + col * 2) ^ ((row & 15) << 4);
        *(unsigned short*)(smem + byte) = f2bf(acc[mt][nt][r4] * inv16);
      }
  __syncthreads();

  // ================= Phase C: einsum eq[n,o,m] = sum_i x[n,i,m]*w[n,i,o] =
  // 16 threads per node; thread q handles output channel o = q.
  const int nloc = tid >> 4;
  const int q = tid & 15;
  const int node = base + nloc;

  const float* xp = feats + (size_t)node * FDIM + 128;

  float eq0 = 0.f, eq1 = 0.f, eq2 = 0.f;

#pragma unroll 2
  for (int i4 = 0; i4 < 8; ++i4) {
    const float* p = xp + i4 * 12;
    f32x4 x0 = *(const f32x4*)(p);
    f32x4 x1 = *(const f32x4*)(p + 4);
    f32x4 x2 = *(const f32x4*)(p + 8);
    float xx[12] = {x0[0], x0[1], x0[2], x0[3], x1[0], x1[1],
                    x1[2], x1[3], x2[0], x2[1], x2[2], x2[3]};
#pragma unroll
    for (int di = 0; di < 4; ++di) {
      int i = i4 * 4 + di;
      int byte = (nloc * 1024 + (i * 16 + q) * 2) ^ ((nloc & 15) << 4);
      float wf = bf2f(*(const unsigned short*)(smem + byte));
      eq0 += xx[di * 3 + 0] * wf;
      eq1 += xx[di * 3 + 1] * wf;
      eq2 += xx[di * 3 + 2] * wf;
    }
  }

  float s = act[node] ? rs32 : 0.f;
  float* op = out + (size_t)node * OUTC + 64 + q * 3;
  __builtin_nontemporal_store(eq0 * s, op + 0);
  __builtin_nontemporal_store(eq1 * s, op + 1);
  __builtin_nontemporal_store(eq2 * s, op + 2);
}

// ---- launch ------------------------------------------------------------
extern "C" void kernel_launch(void* const* d_in, const int* in_sizes, int n_in,
                              void* d_out, int out_size, void* d_ws, size_t ws_size,
                              hipStream_t stream) {
  const float* feats = (const float*)d_in[0];
  const int* ei = (const int*)d_in[1];
  const float* invW1 = (const float*)d_in[2];
  const float* invW2 = (const float*)d_in[3];
  const float* wembW1 = (const float*)d_in[4];
  const float* wembW2 = (const float*)d_in[5];
  float* out = (float*)d_out;

  char* ws = (char*)d_ws;
  unsigned short* W1T = (unsigned short*)ws;                    // 131072 B
  unsigned short* W2T = (unsigned short*)(ws + 131072);         // 294912 B
  unsigned char* act = (unsigned char*)(ws + 131072 + 294912);  // 100000 B

  k_zero<<<98, 256, 0, stream>>>((unsigned int*)act, 25000);
  k_scatter<<<6250, 256, 0, stream>>>(ei, act);
  k_wprep<<<832, 256, 0, stream>>>(invW1, invW2, wembW1, wembW2, W1T, W2T);
  k_main<<<3125, 512, 0, stream>>>(feats, W1T, W2T, act, out);
}

// Round 4
// 246.713 us; speedup vs baseline: 1.2464x; 1.0174x over previous
//
#include <hip/hip_runtime.h>

#define NN 100000
#define EE 1600000
#define FDIM 224
#define OUTC 112
#define XBASE 32768

typedef __attribute__((ext_vector_type(8))) short bf16x8;
typedef __attribute__((ext_vector_type(8))) unsigned short u16x8;
typedef __attribute__((ext_vector_type(4))) float f32x4;
typedef __attribute__((ext_vector_type(2))) float f32x2;
typedef __attribute__((ext_vector_type(2))) unsigned short u16x2;

__device__ __forceinline__ unsigned short f2bf(float f) {
  unsigned u = __builtin_bit_cast(unsigned, f);
  u = (u + 0x7FFFu + ((u >> 16) & 1u)) >> 16;   // RNE
  return (unsigned short)u;
}
__device__ __forceinline__ float bf2f(unsigned short h) {
  return __builtin_bit_cast(float, (unsigned)h << 16);
}

// ---- prep kernels ------------------------------------------------------
__global__ void k_zero(unsigned int* p, int n) {
  int i = blockIdx.x * 256 + threadIdx.x;
  if (i < n) p[i] = 0u;
}

__global__ void k_scatter(const int* __restrict__ ei, unsigned char* __restrict__ act) {
  int e = blockIdx.x * 256 + threadIdx.x;
  if (e < EE) act[ei[e]] = 1;   // ei[0..E) is edge_index[0]
}

// W1T: [512][128] bf16  (cols of [invW1 | wembW1], each row k-contiguous)
// W2T: [576][256] bf16  (rows 0..63 = invW2 cols, 64..575 = wembW2 cols)
__global__ void k_wprep(const float* __restrict__ invW1, const float* __restrict__ invW2,
                        const float* __restrict__ wembW1, const float* __restrict__ wembW2,
                        unsigned short* __restrict__ W1T, unsigned short* __restrict__ W2T) {
  int i = blockIdx.x * 256 + threadIdx.x;
  if (i < 512 * 128) {
    int n = i >> 7, k = i & 127;
    float v = (n < 256) ? invW1[k * 256 + n] : wembW1[k * 256 + (n - 256)];
    W1T[i] = f2bf(v);
  } else if (i < 512 * 128 + 576 * 256) {
    int t = i - 512 * 128;
    int n = t >> 8, k = t & 255;
    float v = (n < 64) ? invW2[k * 64 + n] : wembW2[k * 512 + (n - 64)];
    W2T[t] = f2bf(v);
  }
}

// ---- fused main kernel -------------------------------------------------
// 32 nodes / block, 512 threads (8 waves).
// LDS: [32 rows][512] bf16 H/w region (32KB, XOR swizzle (row&15)<<4)
//      + 6KB x region: 3 planes [m][32 nodes][32 i] bf16 at XBASE.
__global__ __launch_bounds__(512, 4) void k_main(
    const float* __restrict__ feats,
    const unsigned short* __restrict__ W1T,
    const unsigned short* __restrict__ W2T,
    const unsigned char* __restrict__ act,
    float* __restrict__ out) {
  __shared__ char smem[38912];
  const int tid = threadIdx.x;
  const int lane = tid & 63;
  const int wv = tid >> 6;       // wave 0..7
  const int o = lane & 15;       // col within 16x16 tile
  const int g = lane >> 4;       // lane group (k-group / row-group)
  const int base = blockIdx.x * 32;

  const float rs128 = 0.08838834764831845f;   // 1/sqrt(128)
  const float inv16 = 0.0625f;                // 1/sqrt(256)
  const float rs32  = 0.17677669529663687f;   // 1/sqrt(32)

  // ---- issue x_eq loads EARLY (latency hides under phase A) ----------
  // thread handles 6 consecutive floats of node xn's 96-float x row.
  const int xn = tid >> 4;
  const int xs = tid & 15;
  const float* xsrc = feats + (size_t)(base + xn) * FDIM + 128 + xs * 6;
  f32x2 xa = *(const f32x2*)(xsrc);
  f32x2 xb = *(const f32x2*)(xsrc + 2);
  f32x2 xc = *(const f32x2*)(xsrc + 4);

  // ================= Phase A: H = silu(S @ W1cat / sqrt(128)) ==========
  f32x4 acc[2][4];
#pragma unroll
  for (int mt = 0; mt < 2; ++mt)
#pragma unroll
    for (int nt = 0; nt < 4; ++nt)
      acc[mt][nt] = (f32x4){0.f, 0.f, 0.f, 0.f};

  const float* arow0 = feats + (size_t)(base + o) * FDIM;
  const float* arow1 = arow0 + 16 * FDIM;

#pragma unroll 2
  for (int ks = 0; ks < 4; ++ks) {
    bf16x8 af[2];
#pragma unroll
    for (int mt = 0; mt < 2; ++mt) {
      const float* p = (mt ? arow1 : arow0) + ks * 32 + g * 8;
      f32x4 x0 = *(const f32x4*)p;
      f32x4 x1 = *(const f32x4*)(p + 4);
      bf16x8 a;
      a[0] = (short)f2bf(x0[0]); a[1] = (short)f2bf(x0[1]);
      a[2] = (short)f2bf(x0[2]); a[3] = (short)f2bf(x0[3]);
      a[4] = (short)f2bf(x1[0]); a[5] = (short)f2bf(x1[1]);
      a[6] = (short)f2bf(x1[2]); a[7] = (short)f2bf(x1[3]);
      af[mt] = a;
    }
#pragma unroll
    for (int nt = 0; nt < 4; ++nt) {
      int n = wv * 64 + nt * 16 + o;
      bf16x8 b = *(const bf16x8*)(W1T + n * 128 + ks * 32 + g * 8);
#pragma unroll
      for (int mt = 0; mt < 2; ++mt)
        acc[mt][nt] = __builtin_amdgcn_mfma_f32_16x16x32_bf16(af[mt], b, acc[mt][nt], 0, 0, 0);
    }
  }

  // silu + bf16 -> LDS (swizzled)
#pragma unroll
  for (int mt = 0; mt < 2; ++mt)
#pragma unroll
    for (int nt = 0; nt < 4; ++nt)
#pragma unroll
      for (int r4 = 0; r4 < 4; ++r4) {
        int row = mt * 16 + g * 4 + r4;
        int col = wv * 64 + nt * 16 + o;
        float v = acc[mt][nt][r4] * rs128;
        float h = v / (1.f + __expf(-v));
        int byte = (row * 1024 + col * 2) ^ ((row & 15) << 4);
        *(unsigned short*)(smem + byte) = f2bf(h);
      }

  // x -> LDS planes: flat f = xs*6+t, i = f/3, m = f%3.
  {
    int xb0 = XBASE + xn * 64 + xs * 4;
    *(u16x2*)(smem + xb0)          = (u16x2){f2bf(xa[0]), f2bf(xb[1])};  // m=0: i=2xs, 2xs+1
    *(u16x2*)(smem + xb0 + 2048)   = (u16x2){f2bf(xa[1]), f2bf(xc[0])};  // m=1
    *(u16x2*)(smem + xb0 + 4096)   = (u16x2){f2bf(xb[0]), f2bf(xc[1])};  // m=2
  }
  __syncthreads();

  // ====== Phase B (merged): wemb GEMM + inv GEMM over shared ks loop ====
  // inv: one 16x16 tile per wave: rows (wv&1)*16.., cols (wv>>1)*16..
  const int mtw = wv & 1;
  const int ct = wv >> 1;
  f32x4 acc2 = (f32x4){0.f, 0.f, 0.f, 0.f};
#pragma unroll
  for (int mt = 0; mt < 2; ++mt)
#pragma unroll
    for (int nt = 0; nt < 4; ++nt)
      acc[mt][nt] = (f32x4){0.f, 0.f, 0.f, 0.f};

#pragma unroll 2
  for (int ks = 0; ks < 8; ++ks) {
    int rlo = mtw * 16 + o;
    bf16x8 aflo = *(const bf16x8*)(smem + ((rlo * 1024 + ks * 64 + g * 16) ^ ((rlo & 15) << 4)));
    bf16x8 afhi[2];
#pragma unroll
    for (int mt = 0; mt < 2; ++mt) {
      int row = mt * 16 + o;
      afhi[mt] = *(const bf16x8*)(smem + ((row * 1024 + 512 + ks * 64 + g * 16) ^ ((row & 15) << 4)));
    }
    bf16x8 b2 = *(const bf16x8*)(W2T + (ct * 16 + o) * 256 + ks * 32 + g * 8);
    acc2 = __builtin_amdgcn_mfma_f32_16x16x32_bf16(aflo, b2, acc2, 0, 0, 0);
#pragma unroll
    for (int nt = 0; nt < 4; ++nt) {
      int wc = wv * 64 + nt * 16 + o;
      bf16x8 b1 = *(const bf16x8*)(W2T + 16384 + wc * 256 + ks * 32 + g * 8);
#pragma unroll
      for (int mt = 0; mt < 2; ++mt)
        acc[mt][nt] = __builtin_amdgcn_mfma_f32_16x16x32_bf16(afhi[mt], b1, acc[mt][nt], 0, 0, 0);
    }
  }

  // inv output (cols 0..63), masked
#pragma unroll
  for (int r4 = 0; r4 < 4; ++r4) {
    int node = base + mtw * 16 + g * 4 + r4;
    float s = act[node] ? inv16 : 0.f;
    __builtin_nontemporal_store(acc2[r4] * s, out + (size_t)node * OUTC + ct * 16 + o);
  }
  __syncthreads();   // all H reads done -> H region reusable

  // wemb accs -> LDS as bf16 (scaled by 1/16), same swizzle
#pragma unroll
  for (int mt = 0; mt < 2; ++mt)
#pragma unroll
    for (int nt = 0; nt < 4; ++nt)
#pragma unroll
      for (int r4 = 0; r4 < 4; ++r4) {
        int row = mt * 16 + g * 4 + r4;
        int col = wv * 64 + nt * 16 + o;
        int byte = (row * 1024 + col * 2) ^ ((row & 15) << 4);
        *(unsigned short*)(smem + byte) = f2bf(acc[mt][nt][r4] * inv16);
      }
  __syncthreads();

  // ================= Phase C: eq[n,o,m] = sum_i x[m-plane][n][i]*w[n][i,o]
  // 16 threads/node; thread q owns output channel o=q. All LDS, no global.
  const int nloc = tid >> 4;
  const int q = tid & 15;
  const int node = base + nloc;

  float wreg[32];
#pragma unroll
  for (int i = 0; i < 32; ++i) {
    int byte = (nloc * 1024 + (i * 16 + q) * 2) ^ ((nloc & 15) << 4);
    wreg[i] = bf2f(*(const unsigned short*)(smem + byte));
  }

  float eq[3] = {0.f, 0.f, 0.f};
#pragma unroll
  for (int m = 0; m < 3; ++m) {
#pragma unroll
    for (int rb = 0; rb < 4; ++rb) {
      u16x8 ch = *(const u16x8*)(smem + XBASE + m * 2048 + nloc * 64 + rb * 16);
#pragma unroll
      for (int di = 0; di < 8; ++di)
        eq[m] += bf2f(ch[di]) * wreg[rb * 8 + di];
    }
  }

  float s = act[node] ? rs32 : 0.f;
  float* op = out + (size_t)node * OUTC + 64 + q * 3;
  __builtin_nontemporal_store(eq[0] * s, op + 0);
  __builtin_nontemporal_store(eq[1] * s, op + 1);
  __builtin_nontemporal_store(eq[2] * s, op + 2);
}

// ---- launch ------------------------------------------------------------
extern "C" void kernel_launch(void* const* d_in, const int* in_sizes, int n_in,
                              void* d_out, int out_size, void* d_ws, size_t ws_size,
                              hipStream_t stream) {
  const float* feats = (const float*)d_in[0];
  const int* ei = (const int*)d_in[1];
  const float* invW1 = (const float*)d_in[2];
  const float* invW2 = (const float*)d_in[3];
  const float* wembW1 = (const float*)d_in[4];
  const float* wembW2 = (const float*)d_in[5];
  float* out = (float*)d_out;

  char* ws = (char*)d_ws;
  unsigned short* W1T = (unsigned short*)ws;                    // 131072 B
  unsigned short* W2T = (unsigned short*)(ws + 131072);         // 294912 B
  unsigned char* act = (unsigned char*)(ws + 131072 + 294912);  // 100000 B

  k_zero<<<98, 256, 0, stream>>>((unsigned int*)act, 25000);
  k_scatter<<<6250, 256, 0, stream>>>(ei, act);
  k_wprep<<<832, 256, 0, stream>>>(invW1, invW2, wembW1, wembW2, W1T, W2T);
  k_main<<<3125, 512, 0, stream>>>(feats, W1T, W2T, act, out);
}